// Round 9
// baseline (155.669 us; speedup 1.0000x reference)
//
#include <hip/hip_runtime.h>
#include <hip/hip_bf16.h>
#include <math.h>

#define E 128
#define NEI 64
#define THREE_E 384
#define H2BS 136  // bf16 LDS row stride (shorts): 272B, 16B-multiple
#define NPROD 297 // 1 rank + 200 G-chain + 96 wpack

typedef __attribute__((ext_vector_type(8))) short short8;
typedef __attribute__((ext_vector_type(4))) short short4v;
typedef __attribute__((ext_vector_type(4))) float f32x4;

__device__ __forceinline__ float sig_(float x) { return 1.0f / (1.0f + __expf(-x)); }
__device__ __forceinline__ float tanh_(float x) {
    float ax = fabsf(x);
    float e = __expf(-2.0f * ax);
    float r = (1.0f - e) / (1.0f + e);
    return copysignf(r, x);
}
__device__ __forceinline__ short bf16_(float x) {
    __hip_bfloat16 h = __float2bfloat16(x);
    return __builtin_bit_cast(short, h);
}

// One launch: producer blocks (exit early) + consumer blocks (R7 pipeline).
// flags[0] = rank done (1); flags[1] = tables done (== NPROD-1 increments).
__global__ __launch_bounds__(512, 6) void k_all(
    const int* __restrict__ query, const int* __restrict__ support,
    const float* __restrict__ cosr, const int2* __restrict__ edge,
    const float* __restrict__ rel_w, const float* __restrict__ wih,
    const float* __restrict__ whh, const float* __restrict__ bih,
    const float* __restrict__ bhh,
    int* __restrict__ rank, float* __restrict__ G, float* __restrict__ emb1,
    float* __restrict__ GH1, short* __restrict__ wpack, int* __restrict__ flags,
    float* __restrict__ o_tree, float* __restrict__ o_emb,
    float* __restrict__ o_pidx, float* __restrict__ o_pnode,
    float* __restrict__ o_rel, int R, int S) {
    int t = threadIdx.x;
    __shared__ int rankL[256];
    __shared__ int pe[64], prl[64], prl0[64], npe[64], nprl[64];
    __shared__ int hist[256];
    __shared__ int list[4096];
    __shared__ int win_p[64], win_rel[64], win_prel[64];
    __shared__ int s_c, s_lcnt;
    __shared__ __align__(16) short h2b[64][H2BS];

    // ================= producers =================
    if (blockIdx.x < NPROD) {
        int pb = blockIdx.x;
        float* smf = (float*)&h2b[0][0];
        float* grow = smf + 128;
        if (pb == 0) {
            // rank
            if (t < 256) {
                float v = -INFINITY;
                if (t < R)
                    for (int s = 0; s < S; ++s) v = fmaxf(v, cosr[support[s] * R + t]);
                smf[512 + t] = v;
            }
            __syncthreads();
            if (t < 256) {
                int rk = 0;
                if (t < R) {
                    float v = smf[512 + t];
                    for (int r2 = 0; r2 < R; ++r2) {
                        float u = smf[512 + r2];
                        rk += (u > v) || (u == v && r2 < t);
                    }
                }
                rank[t] = rk;
            }
            __syncthreads();
            if (t == 0) {
                __threadfence();
                __hip_atomic_store(&flags[0], 1, __ATOMIC_RELEASE, __HIP_MEMORY_SCOPE_AGENT);
            }
        } else if (pb <= R) {
            int r = pb - 1;
            if (t < E) smf[t] = rel_w[(size_t)r * E + t];
            __syncthreads();
            if (t < THREE_E) {
                float acc = bih[t];
                const float4* w4 = (const float4*)(wih + (size_t)t * E);
#pragma unroll 8
                for (int k = 0; k < E / 4; ++k) {
                    float4 wv = w4[k];
                    acc += smf[4 * k] * wv.x + smf[4 * k + 1] * wv.y + smf[4 * k + 2] * wv.z +
                           smf[4 * k + 3] * wv.w;
                }
                G[(size_t)r * THREE_E + t] = acc;
                grow[t] = acc;
            }
            __syncthreads();
            if (t < E) {
                float rr = sig_(grow[t] + bhh[t]);
                float zz = sig_(grow[E + t] + bhh[E + t]);
                float nn = tanh_(grow[2 * E + t] + rr * bhh[2 * E + t]);
                float h = (1.0f - zz) * nn;
                smf[t] = h;
                emb1[(size_t)r * E + t] = h;
            }
            __syncthreads();
            if (t < THREE_E) {
                float acc = bhh[t];
                const float4* w4 = (const float4*)(whh + (size_t)t * E);
#pragma unroll 8
                for (int k = 0; k < E / 4; ++k) {
                    float4 wv = w4[k];
                    acc += smf[4 * k] * wv.x + smf[4 * k + 1] * wv.y + smf[4 * k + 2] * wv.z +
                           smf[4 * k + 3] * wv.w;
                }
                GH1[(size_t)r * THREE_E + t] = acc;
            }
            __syncthreads();
            if (t == 0) {
                __threadfence();
                atomicAdd(&flags[1], 1);
            }
        } else {
            int idx = (pb - (R + 1)) * 512 + t;  // < 49152
            int i = idx & 7, l = (idx >> 3) & 63, kt = (idx >> 9) & 3, ct = idx >> 11;
            wpack[idx] =
                bf16_(whh[(size_t)(ct * 16 + (l & 15)) * E + kt * 32 + (l >> 4) * 8 + i]);
            __syncthreads();
            if (t == 0) {
                __threadfence();
                atomicAdd(&flags[1], 1);
            }
        }
        return;
    }

    // ================= consumers (R7 pipeline) =================
    int b = blockIdx.x - NPROD;
    const int* edge_i = (const int*)edge;
    int qh = query[b];
    int e1x = 0, e1y = 0;
    if (t < 64) {  // issue step-1 gather; latency hides under flagA wait
        int2 pr = edge[(size_t)qh * NEI + t];
        e1x = pr.x; e1y = pr.y;
    }
    if (t == 0) {  // wait for rank
        while (__hip_atomic_load(&flags[0], __ATOMIC_ACQUIRE, __HIP_MEMORY_SCOPE_AGENT) == 0) {
            __builtin_amdgcn_s_sleep(4);
        }
        __threadfence();
    }
    __syncthreads();
    if (t < 256) rankL[t] = rank[t];
    __syncthreads();
    // ======== step 1: stable sort of 64 ========
    if (t < 64) list[t] = rankL[e1y] * 64 + t;
    __syncthreads();
    if (t < 64) {
        int mykey = list[t], pos = 0;
#pragma unroll
        for (int u = 0; u < 64; ++u) pos += (list[u] < mykey);
        pe[pos] = e1x;
        prl[pos] = e1y;
    }
    if (t < 256) hist[t] = 0;
    if (t == 0) s_lcnt = 0;
    __syncthreads();
    if (t < 64) {
        prl0[t] = prl[t];
        o_tree[(b * 3 + 0) * 64 + t] = (float)pe[t];
        o_pnode[(b * 3 + 0) * 64 + t] = (float)qh;
    }

    // ======== select-2: gather rel-only + hist ========
    int p0 = t >> 6, n0 = t & 63;
    int rl2[8];
#pragma unroll
    for (int u = 0; u < 8; ++u)
        rl2[u] = edge_i[((size_t)pe[p0 + 8 * u] * NEI + n0) * 2 + 1];
#pragma unroll
    for (int u = 0; u < 8; ++u) {
        rl2[u] = rankL[rl2[u]];
        atomicAdd(&hist[rl2[u]], 1);
    }
    __syncthreads();
    if (t < 64) {  // cutoff via wave-0 scan
        int base = 0, c = 255;
        for (int r4 = 0; r4 < 4; ++r4) {
            int sc = hist[r4 * 64 + t];
#pragma unroll
            for (int d = 1; d < 64; d <<= 1) {
                int o = __shfl_up(sc, d, 64);
                if (t >= d) sc += o;
            }
            unsigned long long m = __ballot(base + sc >= 64);
            if (m) { c = r4 * 64 + __ffsll(m) - 1; break; }
            base += __shfl(sc, 63, 64);
        }
        if (t == 0) s_c = c;
    }
    __syncthreads();
    {
        int c = s_c;
#pragma unroll
        for (int u = 0; u < 8; ++u)
            if (rl2[u] <= c) {
                int pos = atomicAdd(&s_lcnt, 1);
                list[pos] = (rl2[u] << 12) | (t + 512 * u);
            }
    }
    __syncthreads();
    int lcnt = s_lcnt;
    if (t < 8 && lcnt + t < 4096) list[lcnt + t] = 0x7fffffff;
    if (t < 256) hist[t] = 0;  // pre-zero for select-3
    __syncthreads();
    {
        int lp = (lcnt + 7) & ~7;
        for (int e = t; e < lcnt; e += 512) {
            int key = list[e], ord = 0;
            for (int f = 0; f < lp; f += 8)
#pragma unroll
                for (int g = 0; g < 8; ++g) ord += (list[f + g] < key);
            if (ord < 64) {
                int i = key & 4095, p = i >> 6, n = i & 63;
                int2 c2 = edge[(size_t)pe[p] * NEI + n];  // re-gather (L2-hit)
                win_rel[ord] = c2.y; win_p[ord] = p; win_prel[ord] = prl[p];
                npe[ord] = c2.x; nprl[ord] = c2.y;
                o_tree[(b * 3 + 1) * 64 + ord] = (float)c2.x;
                o_pnode[(b * 3 + 1) * 64 + ord] = (float)pe[p];
                o_pidx[(b * 3 + 0) * 64 + ord] = (float)p;
                o_rel[(b * 3 + 0) * 64 + ord] = (float)prl[p];
            }
        }
    }
    if (t == 0) s_lcnt = 0;
    __syncthreads();
    if (t < 64) { pe[t] = npe[t]; prl[t] = nprl[t]; }
    __syncthreads();

    // ======== select-3: issue gathers; then wait for tables (usually free) ========
    int rl3[8];
#pragma unroll
    for (int u = 0; u < 8; ++u)
        rl3[u] = edge_i[((size_t)pe[p0 + 8 * u] * NEI + n0) * 2 + 1];
    if (t == 0) {
        while (__hip_atomic_load(&flags[1], __ATOMIC_ACQUIRE, __HIP_MEMORY_SCOPE_AGENT) <
               NPROD - 1) {
            __builtin_amdgcn_s_sleep(4);
        }
        __threadfence();
    }
    __syncthreads();

    // ======== o_emb row0 = emb1[prl0[j]] ========
    {
        int j = t >> 3, q = t & 7;
        const float4* src = (const float4*)(emb1 + (size_t)prl0[j] * E) + q * 4;
        float4* dst = (float4*)(o_emb + ((size_t)(b * 3 + 0) * 64 + j) * E) + q * 4;
#pragma unroll
        for (int v = 0; v < 4; ++v) dst[v] = src[v];
    }

    // ======== GRU-2 -> h2b (bf16 LDS) + o_emb row1 (f32, exact) ========
    {
        int j = t >> 3, q = t & 7;
        int rel = win_rel[j], pr = win_prel[j];
        const float4* Gr = (const float4*)(G + (size_t)rel * THREE_E);
        const float4* Hr = (const float4*)(GH1 + (size_t)pr * THREE_E);
        const float4* h1 = (const float4*)(emb1 + (size_t)pr * E);
        float4* dstg = (float4*)(o_emb + ((size_t)(b * 3 + 1) * 64 + j) * E);
#pragma unroll
        for (int v = 0; v < 4; ++v) {
            int cv = q * 4 + v;
            float4 gr = Gr[cv], gz = Gr[32 + cv], gn = Gr[64 + cv];
            float4 hr = Hr[cv], hz = Hr[32 + cv], hn = Hr[64 + cv];
            float4 h = h1[cv];
            float4 res;
            { float rr = sig_(gr.x + hr.x), zz = sig_(gz.x + hz.x);
              float nn = tanh_(gn.x + rr * hn.x); res.x = (1.0f - zz) * nn + zz * h.x; }
            { float rr = sig_(gr.y + hr.y), zz = sig_(gz.y + hz.y);
              float nn = tanh_(gn.y + rr * hn.y); res.y = (1.0f - zz) * nn + zz * h.y; }
            { float rr = sig_(gr.z + hr.z), zz = sig_(gz.z + hz.z);
              float nn = tanh_(gn.z + rr * hn.z); res.z = (1.0f - zz) * nn + zz * h.z; }
            { float rr = sig_(gr.w + hr.w), zz = sig_(gz.w + hz.w);
              float nn = tanh_(gn.w + rr * hn.w); res.w = (1.0f - zz) * nn + zz * h.w; }
            dstg[cv] = res;
            short4v hb = {bf16_(res.x), bf16_(res.y), bf16_(res.z), bf16_(res.w)};
            *(short4v*)&h2b[j][cv * 4] = hb;
        }
    }

    // ======== select-3: finish ========
#pragma unroll
    for (int u = 0; u < 8; ++u) {
        rl3[u] = rankL[rl3[u]];
        atomicAdd(&hist[rl3[u]], 1);
    }
    __syncthreads();
    if (t < 64) {
        int base = 0, c = 255;
        for (int r4 = 0; r4 < 4; ++r4) {
            int sc = hist[r4 * 64 + t];
#pragma unroll
            for (int d = 1; d < 64; d <<= 1) {
                int o = __shfl_up(sc, d, 64);
                if (t >= d) sc += o;
            }
            unsigned long long m = __ballot(base + sc >= 64);
            if (m) { c = r4 * 64 + __ffsll(m) - 1; break; }
            base += __shfl(sc, 63, 64);
        }
        if (t == 0) s_c = c;
    }
    __syncthreads();
    {
        int c = s_c;
#pragma unroll
        for (int u = 0; u < 8; ++u)
            if (rl3[u] <= c) {
                int pos = atomicAdd(&s_lcnt, 1);
                list[pos] = (rl3[u] << 12) | (t + 512 * u);
            }
    }
    __syncthreads();
    lcnt = s_lcnt;
    if (t < 8 && lcnt + t < 4096) list[lcnt + t] = 0x7fffffff;
    __syncthreads();
    {
        int lp = (lcnt + 7) & ~7;
        for (int e = t; e < lcnt; e += 512) {
            int key = list[e], ord = 0;
            for (int f = 0; f < lp; f += 8)
#pragma unroll
                for (int g = 0; g < 8; ++g) ord += (list[f + g] < key);
            if (ord < 64) {
                int i = key & 4095, p = i >> 6, n = i & 63;
                int2 c2 = edge[(size_t)pe[p] * NEI + n];
                win_rel[ord] = c2.y; win_p[ord] = p;
                o_tree[(b * 3 + 2) * 64 + ord] = (float)c2.x;
                o_pnode[(b * 3 + 2) * 64 + ord] = (float)pe[p];
                o_pidx[(b * 3 + 1) * 64 + ord] = (float)p;
                o_rel[(b * 3 + 1) * 64 + ord] = (float)prl[p];
                o_rel[(b * 3 + 2) * 64 + ord] = (float)c2.y;
            }
        }
    }
    if (t < 64) o_pidx[(b * 3 + 2) * 64 + t] = (float)t;
    __syncthreads();

    // ======== GRU-3: MFMA in two row-halves (no spill at (512,6)) ========
    {
        int lane = t & 63, w = t >> 6;
        int e = w * 16 + (lane & 15);
        float b_r = bhh[e], b_z = bhh[E + e], b_n = bhh[2 * E + e];
#pragma unroll
        for (int half = 0; half < 2; ++half) {
            f32x4 acc[3][2];
#pragma unroll
            for (int g = 0; g < 3; ++g)
#pragma unroll
                for (int rt = 0; rt < 2; ++rt) acc[g][rt] = (f32x4){0.f, 0.f, 0.f, 0.f};
            int pw[2];
#pragma unroll
            for (int rt = 0; rt < 2; ++rt)
                pw[rt] = win_p[(half * 2 + rt) * 16 + (lane & 15)];
#pragma unroll
            for (int kt = 0; kt < 4; ++kt) {
                short8 af[2];
#pragma unroll
                for (int rt = 0; rt < 2; ++rt)
                    af[rt] = *(const short8*)&h2b[pw[rt]][(lane >> 4) * 8 + kt * 32];
#pragma unroll
                for (int g = 0; g < 3; ++g) {
                    short8 bf =
                        *(const short8*)(wpack + ((size_t)((g * 8 + w) * 4 + kt) * 64 + lane) * 8);
#pragma unroll
                    for (int rt = 0; rt < 2; ++rt)
                        acc[g][rt] = __builtin_amdgcn_mfma_f32_16x16x32_bf16(
                            af[rt], bf, acc[g][rt], 0, 0, 0);
                }
            }
#pragma unroll
            for (int rt = 0; rt < 2; ++rt)
#pragma unroll
                for (int reg = 0; reg < 4; ++reg) {
                    int j = (half * 2 + rt) * 16 + (lane >> 4) * 4 + reg;
                    int rel = win_rel[j];
                    float rr = sig_(G[(size_t)rel * THREE_E + e] + acc[0][rt][reg] + b_r);
                    float zz = sig_(G[(size_t)rel * THREE_E + E + e] + acc[1][rt][reg] + b_z);
                    float nn = tanh_(G[(size_t)rel * THREE_E + 2 * E + e] +
                                     rr * (acc[2][rt][reg] + b_n));
                    int p = win_p[j];
                    float h = __bfloat162float(__builtin_bit_cast(__hip_bfloat16, h2b[p][e]));
                    o_emb[((size_t)(b * 3 + 2) * 64 + j) * E + e] = (1.0f - zz) * nn + zz * h;
                }
        }
    }
}

extern "C" void kernel_launch(void* const* d_in, const int* in_sizes, int n_in,
                              void* d_out, int out_size, void* d_ws, size_t ws_size,
                              hipStream_t stream) {
    const int* query = (const int*)d_in[0];
    const int* support = (const int*)d_in[1];
    const float* cosr = (const float*)d_in[2];
    const int2* edge = (const int2*)d_in[3];
    const float* rel_w = (const float*)d_in[4];
    const float* wih = (const float*)d_in[5];
    const float* whh = (const float*)d_in[6];
    const float* bih = (const float*)d_in[7];
    const float* bhh = (const float*)d_in[8];
    int B = in_sizes[0];      // 512
    int S = in_sizes[1];      // 16
    int R = in_sizes[4] / E;  // 200

    float* out = (float*)d_out;
    size_t o_tree = 0;
    size_t o_emb = (size_t)B * 3 * 64;
    size_t o_pidx = o_emb + (size_t)B * 3 * 64 * E;
    size_t o_pnode = o_pidx + (size_t)B * 3 * 64;
    size_t o_rel = o_pnode + (size_t)B * 3 * 64;

    char* ws = (char*)d_ws;
    int* flags = (int*)ws;     ws += 256;  // flags[0]=rank done, flags[1]=tables done
    int* rank = (int*)ws;      ws += 256 * 4;
    float* G = (float*)ws;     ws += (size_t)R * THREE_E * 4;
    float* emb1 = (float*)ws;  ws += (size_t)R * E * 4;
    float* GH1 = (float*)ws;   ws += (size_t)R * THREE_E * 4;
    short* wpack = (short*)ws; ws += (size_t)24 * 4 * 64 * 8 * 2;

    hipMemsetAsync(flags, 0, 2 * sizeof(int), stream);
    k_all<<<NPROD + B, 512, 0, stream>>>(query, support, cosr, edge, rel_w, wih, whh,
                                         bih, bhh, rank, G, emb1, GH1, wpack, flags,
                                         out + o_tree, out + o_emb, out + o_pidx,
                                         out + o_pnode, out + o_rel, R, S);
}

// Round 10
// 65.848 us; speedup vs baseline: 2.3641x; 2.3641x over previous
//
#include <hip/hip_runtime.h>
#include <hip/hip_bf16.h>
#include <math.h>

#define E 128
#define NEI 64
#define THREE_E 384
#define H2BS 136  // bf16 LDS row stride (shorts): 272B, 16B-multiple

typedef __attribute__((ext_vector_type(8))) short short8;
typedef __attribute__((ext_vector_type(4))) short short4v;
typedef __attribute__((ext_vector_type(4))) float f32x4;

__device__ __forceinline__ float sig_(float x) { return 1.0f / (1.0f + __expf(-x)); }
__device__ __forceinline__ float tanh_(float x) {
    float ax = fabsf(x);
    float e = __expf(-2.0f * ax);
    float r = (1.0f - e) / (1.0f + e);
    return copysignf(r, x);
}
__device__ __forceinline__ short bf16_(float x) {
    __hip_bfloat16 h = __float2bfloat16(x);
    return __builtin_bit_cast(short, h);
}

// ================= kernel 1: producers (tables) || selects (top-k front-end) ===============
// blk < R:          G[r] -> emb1[r] -> GH1[r]
// R <= blk < R+96:  wpack
// blk >= R+96:      select front-end for batch b = blk-(R+96); per-block rank;
//                   writes all int outputs + winner metadata to ws.
__global__ __launch_bounds__(512, 6) void k_front(
    const int* __restrict__ query, const int* __restrict__ support,
    const float* __restrict__ cosr, const int2* __restrict__ edge,
    const float* __restrict__ rel_w, const float* __restrict__ wih,
    const float* __restrict__ whh, const float* __restrict__ bih,
    const float* __restrict__ bhh,
    float* __restrict__ G, float* __restrict__ emb1, float* __restrict__ GH1,
    short* __restrict__ wpack,
    int* __restrict__ m_prl0, int* __restrict__ m_w2rel, int* __restrict__ m_w2prel,
    int* __restrict__ m_w3rel, int* __restrict__ m_w3p,
    float* __restrict__ o_tree, float* __restrict__ o_pidx,
    float* __restrict__ o_pnode, float* __restrict__ o_rel, int R, int S) {
    int t = threadIdx.x;
    __shared__ int rankL[256];
    __shared__ int peU[64], prlU[64], pe[64], prl[64], posOf[64], npe[64], nprl[64];
    __shared__ int hist[256];
    __shared__ int list[4096];
    __shared__ int s_c, s_lcnt;
    float* smf = (float*)list;  // producer scratch / rank mxc (aliased, pre-list use)

    if (blockIdx.x < R) {  // -------- G-chain producer --------
        int r = blockIdx.x;
        float* grow = smf + 128;
        if (t < E) smf[t] = rel_w[(size_t)r * E + t];
        __syncthreads();
        if (t < THREE_E) {
            float acc = bih[t];
            const float4* w4 = (const float4*)(wih + (size_t)t * E);
#pragma unroll 8
            for (int k = 0; k < E / 4; ++k) {
                float4 wv = w4[k];
                acc += smf[4 * k] * wv.x + smf[4 * k + 1] * wv.y + smf[4 * k + 2] * wv.z +
                       smf[4 * k + 3] * wv.w;
            }
            G[(size_t)r * THREE_E + t] = acc;
            grow[t] = acc;
        }
        __syncthreads();
        if (t < E) {
            float rr = sig_(grow[t] + bhh[t]);
            float zz = sig_(grow[E + t] + bhh[E + t]);
            float nn = tanh_(grow[2 * E + t] + rr * bhh[2 * E + t]);
            float h = (1.0f - zz) * nn;
            smf[t] = h;
            emb1[(size_t)r * E + t] = h;
        }
        __syncthreads();
        if (t < THREE_E) {
            float acc = bhh[t];
            const float4* w4 = (const float4*)(whh + (size_t)t * E);
#pragma unroll 8
            for (int k = 0; k < E / 4; ++k) {
                float4 wv = w4[k];
                acc += smf[4 * k] * wv.x + smf[4 * k + 1] * wv.y + smf[4 * k + 2] * wv.z +
                       smf[4 * k + 3] * wv.w;
            }
            GH1[(size_t)r * THREE_E + t] = acc;
        }
        return;
    }
    if (blockIdx.x < R + 96) {  // -------- wpack producer --------
        int idx = (blockIdx.x - R) * 512 + t;  // < 49152
        int i = idx & 7, l = (idx >> 3) & 63, kt = (idx >> 9) & 3, ct = idx >> 11;
        wpack[idx] = bf16_(whh[(size_t)(ct * 16 + (l & 15)) * E + kt * 32 + (l >> 4) * 8 + i]);
        return;
    }

    // ================= select front-end =================
    int b = blockIdx.x - (R + 96);
    const int* edge_i = (const int*)edge;
    int qh = query[b];
    if (t < 64) {  // step-1 gather -> LDS (unsorted)
        int2 pr = edge[(size_t)qh * NEI + t];
        peU[t] = pr.x;
        prlU[t] = pr.y;
    }
    // per-block rank: max over support rows (overlaps step-1 gather)
    float v = -INFINITY;
    if (t < R)
        for (int s = 0; s < S; ++s) v = fmaxf(v, cosr[support[s] * R + t]);
    __syncthreads();  // peU/prlU visible

    // select-2 gathers on UNSORTED parents (latency hides under rank+sort)
    int p0 = t >> 6, n0 = t & 63;
    int rl2[8];
#pragma unroll
    for (int u = 0; u < 8; ++u)
        rl2[u] = edge_i[((size_t)peU[p0 + 8 * u] * NEI + n0) * 2 + 1];

    if (t < 256) smf[t] = v;  // mxc
    __syncthreads();
    {
        int rk = 0;
        if (t < R) {
            float vv = smf[t];
            for (int r2 = 0; r2 < R; ++r2) {
                float u = smf[r2];
                rk += (u > vv) || (u == vv && r2 < t);
            }
        }
        if (t < 256) rankL[t] = rk;
        if (t < 256) hist[t] = 0;
        if (t == 0) s_lcnt = 0;
    }
    __syncthreads();
    // step-1 stable sort
    if (t < 64) {
        int mykey = rankL[prlU[t]] * 64 + t;
        list[256 + t] = mykey;  // avoid smf alias region [0,256)
    }
    __syncthreads();
    if (t < 64) {
        int mykey = list[256 + t], pos = 0;
#pragma unroll
        for (int u = 0; u < 64; ++u) pos += (list[256 + u] < mykey);
        pe[pos] = peU[t];
        prl[pos] = prlU[t];
        posOf[t] = pos;
        m_prl0[b * 64 + pos] = prlU[t];
    }
    __syncthreads();
    if (t < 64) {
        o_tree[(b * 3 + 0) * 64 + t] = (float)pe[t];
        o_pnode[(b * 3 + 0) * 64 + t] = (float)qh;
        o_pidx[(b * 3 + 2) * 64 + t] = (float)t;
    }
    // select-2: hist
#pragma unroll
    for (int u = 0; u < 8; ++u) {
        rl2[u] = rankL[rl2[u]];
        atomicAdd(&hist[rl2[u]], 1);
    }
    __syncthreads();
    if (t < 64) {  // cutoff via wave-0 scan
        int base = 0, c = 255;
        for (int r4 = 0; r4 < 4; ++r4) {
            int sc = hist[r4 * 64 + t];
#pragma unroll
            for (int d = 1; d < 64; d <<= 1) {
                int o = __shfl_up(sc, d, 64);
                if (t >= d) sc += o;
            }
            unsigned long long m = __ballot(base + sc >= 64);
            if (m) { c = r4 * 64 + __ffsll(m) - 1; break; }
            base += __shfl(sc, 63, 64);
        }
        if (t == 0) s_c = c;
    }
    __syncthreads();
    {
        int c = s_c;
#pragma unroll
        for (int u = 0; u < 8; ++u)
            if (rl2[u] <= c) {
                int pos = atomicAdd(&s_lcnt, 1);
                list[pos] = (rl2[u] << 12) | (posOf[p0 + 8 * u] << 6) | n0;
            }
    }
    __syncthreads();
    int lcnt = s_lcnt;
    if (t < 8 && lcnt + t < 4096) list[lcnt + t] = 0x7fffffff;
    if (t < 256) hist[t] = 0;  // pre-zero for select-3
    __syncthreads();
    {
        int lp = (lcnt + 7) & ~7;
        for (int e = t; e < lcnt; e += 512) {
            int key = list[e], ord = 0;
            for (int f = 0; f < lp; f += 8)
#pragma unroll
                for (int g = 0; g < 8; ++g) ord += (list[f + g] < key);
            if (ord < 64) {
                int i = key & 4095, p = i >> 6, n = i & 63;
                int2 c2 = edge[(size_t)pe[p] * NEI + n];  // re-gather (cache-hit)
                npe[ord] = c2.x;
                nprl[ord] = c2.y;
                m_w2rel[b * 64 + ord] = c2.y;
                m_w2prel[b * 64 + ord] = prl[p];
                o_tree[(b * 3 + 1) * 64 + ord] = (float)c2.x;
                o_pnode[(b * 3 + 1) * 64 + ord] = (float)pe[p];
                o_pidx[(b * 3 + 0) * 64 + ord] = (float)p;
                o_rel[(b * 3 + 0) * 64 + ord] = (float)prl[p];
            }
        }
    }
    if (t == 0) s_lcnt = 0;
    __syncthreads();

    // select-3 (parents already sorted: npe)
    int rl3[8];
#pragma unroll
    for (int u = 0; u < 8; ++u)
        rl3[u] = edge_i[((size_t)npe[p0 + 8 * u] * NEI + n0) * 2 + 1];
#pragma unroll
    for (int u = 0; u < 8; ++u) {
        rl3[u] = rankL[rl3[u]];
        atomicAdd(&hist[rl3[u]], 1);
    }
    __syncthreads();
    if (t < 64) {
        int base = 0, c = 255;
        for (int r4 = 0; r4 < 4; ++r4) {
            int sc = hist[r4 * 64 + t];
#pragma unroll
            for (int d = 1; d < 64; d <<= 1) {
                int o = __shfl_up(sc, d, 64);
                if (t >= d) sc += o;
            }
            unsigned long long m = __ballot(base + sc >= 64);
            if (m) { c = r4 * 64 + __ffsll(m) - 1; break; }
            base += __shfl(sc, 63, 64);
        }
        if (t == 0) s_c = c;
    }
    __syncthreads();
    {
        int c = s_c;
#pragma unroll
        for (int u = 0; u < 8; ++u)
            if (rl3[u] <= c) {
                int pos = atomicAdd(&s_lcnt, 1);
                list[pos] = (rl3[u] << 12) | (t + 512 * u);
            }
    }
    __syncthreads();
    lcnt = s_lcnt;
    if (t < 8 && lcnt + t < 4096) list[lcnt + t] = 0x7fffffff;
    __syncthreads();
    {
        int lp = (lcnt + 7) & ~7;
        for (int e = t; e < lcnt; e += 512) {
            int key = list[e], ord = 0;
            for (int f = 0; f < lp; f += 8)
#pragma unroll
                for (int g = 0; g < 8; ++g) ord += (list[f + g] < key);
            if (ord < 64) {
                int i = key & 4095, p = i >> 6, n = i & 63;
                int2 c2 = edge[(size_t)npe[p] * NEI + n];
                m_w3rel[b * 64 + ord] = c2.y;
                m_w3p[b * 64 + ord] = p;
                o_tree[(b * 3 + 2) * 64 + ord] = (float)c2.x;
                o_pnode[(b * 3 + 2) * 64 + ord] = (float)npe[p];
                o_pidx[(b * 3 + 1) * 64 + ord] = (float)p;
                o_rel[(b * 3 + 1) * 64 + ord] = (float)nprl[p];
                o_rel[(b * 3 + 2) * 64 + ord] = (float)c2.y;
            }
        }
    }
}

// ================= kernel 2: GRU back-end (tables + metadata -> o_emb) =================
__global__ __launch_bounds__(512, 6) void k_gru(
    const float* __restrict__ G, const float* __restrict__ GH1,
    const float* __restrict__ emb1, const short* __restrict__ wpack,
    const float* __restrict__ bhh,
    const int* __restrict__ m_prl0, const int* __restrict__ m_w2rel,
    const int* __restrict__ m_w2prel, const int* __restrict__ m_w3rel,
    const int* __restrict__ m_w3p, float* __restrict__ o_emb) {
    int b = blockIdx.x, t = threadIdx.x;
    __shared__ __align__(16) short h2b[64][H2BS];
    __shared__ int w3p_l[64], w3r_l[64];

    int j = t >> 3, q = t & 7;
    int prl0j = m_prl0[b * 64 + j];
    int w2r = m_w2rel[b * 64 + j];
    int w2p = m_w2prel[b * 64 + j];
    if (t < 64) {
        w3p_l[t] = m_w3p[b * 64 + t];
        w3r_l[t] = m_w3rel[b * 64 + t];
    }

    // o_emb row0 = emb1[prl0[j]]
    {
        const float4* src = (const float4*)(emb1 + (size_t)prl0j * E) + q * 4;
        float4* dst = (float4*)(o_emb + ((size_t)(b * 3 + 0) * 64 + j) * E) + q * 4;
#pragma unroll
        for (int v = 0; v < 4; ++v) dst[v] = src[v];
    }

    // GRU-2 -> h2b (bf16 LDS) + o_emb row1 (f32, exact)
    {
        const float4* Gr = (const float4*)(G + (size_t)w2r * THREE_E);
        const float4* Hr = (const float4*)(GH1 + (size_t)w2p * THREE_E);
        const float4* h1 = (const float4*)(emb1 + (size_t)w2p * E);
        float4* dstg = (float4*)(o_emb + ((size_t)(b * 3 + 1) * 64 + j) * E);
#pragma unroll
        for (int v = 0; v < 4; ++v) {
            int cv = q * 4 + v;
            float4 gr = Gr[cv], gz = Gr[32 + cv], gn = Gr[64 + cv];
            float4 hr = Hr[cv], hz = Hr[32 + cv], hn = Hr[64 + cv];
            float4 h = h1[cv];
            float4 res;
            { float rr = sig_(gr.x + hr.x), zz = sig_(gz.x + hz.x);
              float nn = tanh_(gn.x + rr * hn.x); res.x = (1.0f - zz) * nn + zz * h.x; }
            { float rr = sig_(gr.y + hr.y), zz = sig_(gz.y + hz.y);
              float nn = tanh_(gn.y + rr * hn.y); res.y = (1.0f - zz) * nn + zz * h.y; }
            { float rr = sig_(gr.z + hr.z), zz = sig_(gz.z + hz.z);
              float nn = tanh_(gn.z + rr * hn.z); res.z = (1.0f - zz) * nn + zz * h.z; }
            { float rr = sig_(gr.w + hr.w), zz = sig_(gz.w + hz.w);
              float nn = tanh_(gn.w + rr * hn.w); res.w = (1.0f - zz) * nn + zz * h.w; }
            dstg[cv] = res;
            short4v hb = {bf16_(res.x), bf16_(res.y), bf16_(res.z), bf16_(res.w)};
            *(short4v*)&h2b[j][cv * 4] = hb;
        }
    }
    __syncthreads();

    // GRU-3: MFMA in two row-halves
    {
        int lane = t & 63, w = t >> 6;
        int e = w * 16 + (lane & 15);
        float b_r = bhh[e], b_z = bhh[E + e], b_n = bhh[2 * E + e];
#pragma unroll
        for (int half = 0; half < 2; ++half) {
            f32x4 acc[3][2];
#pragma unroll
            for (int g = 0; g < 3; ++g)
#pragma unroll
                for (int rt = 0; rt < 2; ++rt) acc[g][rt] = (f32x4){0.f, 0.f, 0.f, 0.f};
            int pw[2];
#pragma unroll
            for (int rt = 0; rt < 2; ++rt)
                pw[rt] = w3p_l[(half * 2 + rt) * 16 + (lane & 15)];
#pragma unroll
            for (int kt = 0; kt < 4; ++kt) {
                short8 af[2];
#pragma unroll
                for (int rt = 0; rt < 2; ++rt)
                    af[rt] = *(const short8*)&h2b[pw[rt]][(lane >> 4) * 8 + kt * 32];
#pragma unroll
                for (int g = 0; g < 3; ++g) {
                    short8 bf =
                        *(const short8*)(wpack + ((size_t)((g * 8 + w) * 4 + kt) * 64 + lane) * 8);
#pragma unroll
                    for (int rt = 0; rt < 2; ++rt)
                        acc[g][rt] = __builtin_amdgcn_mfma_f32_16x16x32_bf16(
                            af[rt], bf, acc[g][rt], 0, 0, 0);
                }
            }
#pragma unroll
            for (int rt = 0; rt < 2; ++rt)
#pragma unroll
                for (int reg = 0; reg < 4; ++reg) {
                    int jj = (half * 2 + rt) * 16 + (lane >> 4) * 4 + reg;
                    int rel = w3r_l[jj];
                    float rr = sig_(G[(size_t)rel * THREE_E + e] + acc[0][rt][reg] + b_r);
                    float zz = sig_(G[(size_t)rel * THREE_E + E + e] + acc[1][rt][reg] + b_z);
                    float nn = tanh_(G[(size_t)rel * THREE_E + 2 * E + e] +
                                     rr * (acc[2][rt][reg] + b_n));
                    int p = w3p_l[jj];
                    float h = __bfloat162float(__builtin_bit_cast(__hip_bfloat16, h2b[p][e]));
                    o_emb[((size_t)(b * 3 + 2) * 64 + jj) * E + e] = (1.0f - zz) * nn + zz * h;
                }
        }
    }
}

extern "C" void kernel_launch(void* const* d_in, const int* in_sizes, int n_in,
                              void* d_out, int out_size, void* d_ws, size_t ws_size,
                              hipStream_t stream) {
    const int* query = (const int*)d_in[0];
    const int* support = (const int*)d_in[1];
    const float* cosr = (const float*)d_in[2];
    const int2* edge = (const int2*)d_in[3];
    const float* rel_w = (const float*)d_in[4];
    const float* wih = (const float*)d_in[5];
    const float* whh = (const float*)d_in[6];
    const float* bih = (const float*)d_in[7];
    const float* bhh = (const float*)d_in[8];
    int B = in_sizes[0];      // 512
    int S = in_sizes[1];      // 16
    int R = in_sizes[4] / E;  // 200

    float* out = (float*)d_out;
    size_t o_tree = 0;
    size_t o_emb = (size_t)B * 3 * 64;
    size_t o_pidx = o_emb + (size_t)B * 3 * 64 * E;
    size_t o_pnode = o_pidx + (size_t)B * 3 * 64;
    size_t o_rel = o_pnode + (size_t)B * 3 * 64;

    char* ws = (char*)d_ws;
    float* G = (float*)ws;      ws += (size_t)R * THREE_E * 4;
    float* emb1 = (float*)ws;   ws += (size_t)R * E * 4;
    float* GH1 = (float*)ws;    ws += (size_t)R * THREE_E * 4;
    short* wpack = (short*)ws;  ws += (size_t)24 * 4 * 64 * 8 * 2;
    int* m_prl0 = (int*)ws;     ws += (size_t)B * 64 * 4;
    int* m_w2rel = (int*)ws;    ws += (size_t)B * 64 * 4;
    int* m_w2prel = (int*)ws;   ws += (size_t)B * 64 * 4;
    int* m_w3rel = (int*)ws;    ws += (size_t)B * 64 * 4;
    int* m_w3p = (int*)ws;      ws += (size_t)B * 64 * 4;

    k_front<<<R + 96 + B, 512, 0, stream>>>(query, support, cosr, edge, rel_w, wih,
                                            whh, bih, bhh, G, emb1, GH1, wpack,
                                            m_prl0, m_w2rel, m_w2prel, m_w3rel, m_w3p,
                                            out + o_tree, out + o_pidx,
                                            out + o_pnode, out + o_rel, R, S);
    k_gru<<<B, 512, 0, stream>>>(G, GH1, emb1, wpack, bhh,
                                 m_prl0, m_w2rel, m_w2prel, m_w3rel, m_w3p,
                                 out + o_emb);
}

// Round 11
// 46.851 us; speedup vs baseline: 3.3226x; 1.4055x over previous
//
#include <hip/hip_runtime.h>
#include <hip/hip_bf16.h>
#include <math.h>

#define E 128
#define NEI 64
#define THREE_E 384
#define H2BS 136  // bf16 LDS row stride (shorts): 272B, 16B-multiple

typedef __attribute__((ext_vector_type(8))) short short8;
typedef __attribute__((ext_vector_type(4))) short short4v;
typedef __attribute__((ext_vector_type(4))) float f32x4;

__device__ __forceinline__ float sig_(float x) { return 1.0f / (1.0f + __expf(-x)); }
__device__ __forceinline__ float tanh_(float x) {
    float ax = fabsf(x);
    float e = __expf(-2.0f * ax);
    float r = (1.0f - e) / (1.0f + e);
    return copysignf(r, x);
}
__device__ __forceinline__ short bf16_(float x) {
    __hip_bfloat16 h = __float2bfloat16(x);
    return __builtin_bit_cast(short, h);
}

// ---- kAB: all precompute in one launch (R7-proven). ----
__global__ __launch_bounds__(512) void kAB(
    const int* __restrict__ support, const float* __restrict__ cosr,
    int* __restrict__ rank, int S, int R,
    const float* __restrict__ rel_w, const float* __restrict__ wih,
    const float* __restrict__ bih, float* __restrict__ G,
    const float* __restrict__ whh, const float* __restrict__ bhh,
    float* __restrict__ emb1, float* __restrict__ GH1,
    short* __restrict__ wpack) {
    int blk = blockIdx.x, t = threadIdx.x;
    __shared__ float sm[256];
    __shared__ float grow[THREE_E];
    if (blk < R) {
        int r = blk;
        if (t < E) sm[t] = rel_w[(size_t)r * E + t];
        __syncthreads();
        if (t < THREE_E) {
            float acc = bih[t];
            const float4* w4 = (const float4*)(wih + (size_t)t * E);
#pragma unroll 8
            for (int k = 0; k < E / 4; ++k) {
                float4 wv = w4[k];
                acc += sm[4 * k] * wv.x + sm[4 * k + 1] * wv.y + sm[4 * k + 2] * wv.z +
                       sm[4 * k + 3] * wv.w;
            }
            G[(size_t)r * THREE_E + t] = acc;
            grow[t] = acc;
        }
        __syncthreads();
        if (t < E) {
            float rr = sig_(grow[t] + bhh[t]);
            float zz = sig_(grow[E + t] + bhh[E + t]);
            float nn = tanh_(grow[2 * E + t] + rr * bhh[2 * E + t]);
            float h = (1.0f - zz) * nn;
            sm[t] = h;
            emb1[(size_t)r * E + t] = h;
        }
        __syncthreads();
        if (t < THREE_E) {
            float acc = bhh[t];
            const float4* w4 = (const float4*)(whh + (size_t)t * E);
#pragma unroll 8
            for (int k = 0; k < E / 4; ++k) {
                float4 wv = w4[k];
                acc += sm[4 * k] * wv.x + sm[4 * k + 1] * wv.y + sm[4 * k + 2] * wv.z +
                       sm[4 * k + 3] * wv.w;
            }
            GH1[(size_t)r * THREE_E + t] = acc;
        }
    } else if (blk < R + 96) {
        int idx = (blk - R) * 512 + t;  // < 49152
        int i = idx & 7, l = (idx >> 3) & 63, kt = (idx >> 9) & 3, ct = idx >> 11;
        wpack[idx] = bf16_(whh[(size_t)(ct * 16 + (l & 15)) * E + kt * 32 + (l >> 4) * 8 + i]);
    } else {
        if (t < 256) {
            float v = -INFINITY;
            if (t < R)
                for (int s = 0; s < S; ++s) v = fmaxf(v, cosr[support[s] * R + t]);
            sm[t] = v;
        }
        __syncthreads();
        if (t < 256) {
            int rk = 0;
            if (t < R) {
                float v = sm[t];
                for (int r2 = 0; r2 < R; ++r2) {
                    float u = sm[r2];
                    rk += (u > v) || (u == v && r2 < t);
                }
            }
            rank[t] = rk;
        }
    }
}

// ---- fused main: steps 1+2+3 per block, 1024 threads (16 waves, 2 blocks/CU) ----
__global__ __launch_bounds__(1024, 8) void k_main(
    const int* __restrict__ query, const int2* __restrict__ edge,
    const int* __restrict__ rank, const float* __restrict__ G,
    const float* __restrict__ GH1, const float* __restrict__ emb1,
    const short* __restrict__ wpack, const float* __restrict__ bhh,
    float* __restrict__ o_tree, float* __restrict__ o_emb,
    float* __restrict__ o_pidx, float* __restrict__ o_pnode,
    float* __restrict__ o_rel) {
    int b = blockIdx.x, t = threadIdx.x;
    __shared__ int rankL[256];
    __shared__ int pe[64], prl[64], npe[64], nprl[64];
    __shared__ int hist[256];
    __shared__ int list[4096];
    __shared__ int win_p[64], win_rel[64], win_prel[64];
    __shared__ int s_c, s_lcnt;
    __shared__ __align__(16) short h2b[64][H2BS];

    const int* edge_i = (const int*)edge;  // rel word = edge_i[2*idx+1]
    if (t < 256) rankL[t] = rank[t];
    int qh = query[b];
    int e1x = 0, e1y = 0;
    if (t < 64) {
        int2 pr = edge[(size_t)qh * NEI + t];
        e1x = pr.x; e1y = pr.y;
    }
    __syncthreads();
    // ======== step 1: stable sort of 64 ========
    if (t < 64) list[t] = rankL[e1y] * 64 + t;
    __syncthreads();
    if (t < 64) {
        int mykey = list[t], pos = 0;
#pragma unroll
        for (int u = 0; u < 64; ++u) pos += (list[u] < mykey);
        pe[pos] = e1x;
        prl[pos] = e1y;
    }
    if (t < 256) hist[t] = 0;
    if (t == 0) s_lcnt = 0;
    __syncthreads();

    // ======== select-2: gather rel-only (4/thread) ========
    int p0 = t >> 6, n0 = t & 63;  // p0 in 0..15
    int rl2[4];
#pragma unroll
    for (int u = 0; u < 4; ++u)
        rl2[u] = edge_i[((size_t)pe[p0 + 16 * u] * NEI + n0) * 2 + 1];
    // step-1 outputs overlap gather latency
    if (t < 64) {
        o_tree[(b * 3 + 0) * 64 + t] = (float)pe[t];
        o_pnode[(b * 3 + 0) * 64 + t] = (float)qh;
    }
    {
        int j = t >> 4, q = t & 15;
        const float4* src = (const float4*)(emb1 + (size_t)prl[j] * E) + q * 2;
        float4* dst = (float4*)(o_emb + ((size_t)(b * 3 + 0) * 64 + j) * E) + q * 2;
        dst[0] = src[0];
        dst[1] = src[1];
    }
#pragma unroll
    for (int u = 0; u < 4; ++u) {
        rl2[u] = rankL[rl2[u]];
        atomicAdd(&hist[rl2[u]], 1);
    }
    __syncthreads();
    if (t < 64) {  // cutoff via wave-0 scan
        int base = 0, c = 255;
        for (int r4 = 0; r4 < 4; ++r4) {
            int sc = hist[r4 * 64 + t];
#pragma unroll
            for (int d = 1; d < 64; d <<= 1) {
                int o = __shfl_up(sc, d, 64);
                if (t >= d) sc += o;
            }
            unsigned long long m = __ballot(base + sc >= 64);
            if (m) { c = r4 * 64 + __ffsll(m) - 1; break; }
            base += __shfl(sc, 63, 64);
        }
        if (t == 0) s_c = c;
    }
    __syncthreads();
    {
        int c = s_c;
#pragma unroll
        for (int u = 0; u < 4; ++u)
            if (rl2[u] <= c) {
                int pos = atomicAdd(&s_lcnt, 1);
                list[pos] = (rl2[u] << 12) | (t + 1024 * u);
            }
    }
    __syncthreads();
    int lcnt = s_lcnt;
    if (t < 8 && lcnt + t < 4096) list[lcnt + t] = 0x7fffffff;
    if (t < 256) hist[t] = 0;  // pre-zero for select-3
    __syncthreads();
    {
        int lp = (lcnt + 7) & ~7;
        for (int e = t; e < lcnt; e += 1024) {
            int key = list[e], ord = 0;
            for (int f = 0; f < lp; f += 8)
#pragma unroll
                for (int g = 0; g < 8; ++g) ord += (list[f + g] < key);
            if (ord < 64) {
                int i = key & 4095, p = i >> 6, n = i & 63;
                int2 c2 = edge[(size_t)pe[p] * NEI + n];  // re-gather (cache-hit)
                win_rel[ord] = c2.y; win_p[ord] = p; win_prel[ord] = prl[p];
                npe[ord] = c2.x; nprl[ord] = c2.y;
                o_tree[(b * 3 + 1) * 64 + ord] = (float)c2.x;
                o_pnode[(b * 3 + 1) * 64 + ord] = (float)pe[p];
                o_pidx[(b * 3 + 0) * 64 + ord] = (float)p;
                o_rel[(b * 3 + 0) * 64 + ord] = (float)prl[p];
            }
        }
    }
    if (t == 0) s_lcnt = 0;
    __syncthreads();
    if (t < 64) { pe[t] = npe[t]; prl[t] = nprl[t]; }
    __syncthreads();

    // ======== select-3: issue gathers NOW (hide under GRU-2) ========
    int rl3[4];
#pragma unroll
    for (int u = 0; u < 4; ++u)
        rl3[u] = edge_i[((size_t)pe[p0 + 16 * u] * NEI + n0) * 2 + 1];

    // ======== GRU-2 -> h2b (bf16 LDS) + o_emb row1 (f32, exact) ========
    {
        int j = t >> 4, q = t & 15;
        int rel = win_rel[j], pr = win_prel[j];
        const float4* Gr = (const float4*)(G + (size_t)rel * THREE_E);
        const float4* Hr = (const float4*)(GH1 + (size_t)pr * THREE_E);
        const float4* h1 = (const float4*)(emb1 + (size_t)pr * E);
        float4* dstg = (float4*)(o_emb + ((size_t)(b * 3 + 1) * 64 + j) * E);
#pragma unroll
        for (int v = 0; v < 2; ++v) {
            int cv = q * 2 + v;
            float4 gr = Gr[cv], gz = Gr[32 + cv], gn = Gr[64 + cv];
            float4 hr = Hr[cv], hz = Hr[32 + cv], hn = Hr[64 + cv];
            float4 h = h1[cv];
            float4 res;
            { float rr = sig_(gr.x + hr.x), zz = sig_(gz.x + hz.x);
              float nn = tanh_(gn.x + rr * hn.x); res.x = (1.0f - zz) * nn + zz * h.x; }
            { float rr = sig_(gr.y + hr.y), zz = sig_(gz.y + hz.y);
              float nn = tanh_(gn.y + rr * hn.y); res.y = (1.0f - zz) * nn + zz * h.y; }
            { float rr = sig_(gr.z + hr.z), zz = sig_(gz.z + hz.z);
              float nn = tanh_(gn.z + rr * hn.z); res.z = (1.0f - zz) * nn + zz * h.z; }
            { float rr = sig_(gr.w + hr.w), zz = sig_(gz.w + hz.w);
              float nn = tanh_(gn.w + rr * hn.w); res.w = (1.0f - zz) * nn + zz * h.w; }
            dstg[cv] = res;
            short4v hb = {bf16_(res.x), bf16_(res.y), bf16_(res.z), bf16_(res.w)};
            *(short4v*)&h2b[j][cv * 4] = hb;
        }
    }
#pragma unroll
    for (int u = 0; u < 4; ++u) {
        rl3[u] = rankL[rl3[u]];
        atomicAdd(&hist[rl3[u]], 1);
    }
    __syncthreads();
    if (t < 64) {
        int base = 0, c = 255;
        for (int r4 = 0; r4 < 4; ++r4) {
            int sc = hist[r4 * 64 + t];
#pragma unroll
            for (int d = 1; d < 64; d <<= 1) {
                int o = __shfl_up(sc, d, 64);
                if (t >= d) sc += o;
            }
            unsigned long long m = __ballot(base + sc >= 64);
            if (m) { c = r4 * 64 + __ffsll(m) - 1; break; }
            base += __shfl(sc, 63, 64);
        }
        if (t == 0) s_c = c;
    }
    __syncthreads();
    {
        int c = s_c;
#pragma unroll
        for (int u = 0; u < 4; ++u)
            if (rl3[u] <= c) {
                int pos = atomicAdd(&s_lcnt, 1);
                list[pos] = (rl3[u] << 12) | (t + 1024 * u);
            }
    }
    __syncthreads();
    lcnt = s_lcnt;
    if (t < 8 && lcnt + t < 4096) list[lcnt + t] = 0x7fffffff;
    __syncthreads();
    {
        int lp = (lcnt + 7) & ~7;
        for (int e = t; e < lcnt; e += 1024) {
            int key = list[e], ord = 0;
            for (int f = 0; f < lp; f += 8)
#pragma unroll
                for (int g = 0; g < 8; ++g) ord += (list[f + g] < key);
            if (ord < 64) {
                int i = key & 4095, p = i >> 6, n = i & 63;
                int2 c2 = edge[(size_t)pe[p] * NEI + n];
                win_rel[ord] = c2.y; win_p[ord] = p;
                o_tree[(b * 3 + 2) * 64 + ord] = (float)c2.x;
                o_pnode[(b * 3 + 2) * 64 + ord] = (float)pe[p];
                o_pidx[(b * 3 + 1) * 64 + ord] = (float)p;
                o_rel[(b * 3 + 1) * 64 + ord] = (float)prl[p];
                o_rel[(b * 3 + 2) * 64 + ord] = (float)c2.y;
            }
        }
    }
    if (t < 64) o_pidx[(b * 3 + 2) * 64 + t] = (float)t;
    __syncthreads();

    // ======== GRU-3: MFMA; row-halves split ACROSS wave groups (16 waves) ========
    {
        int lane = t & 63, w = t >> 6;      // w in 0..15
        int half = w >> 3, ww = w & 7;      // waves 0-7: rows 0-31; waves 8-15: rows 32-63
        int e = ww * 16 + (lane & 15);
        float b_r = bhh[e], b_z = bhh[E + e], b_n = bhh[2 * E + e];
        f32x4 acc[3][2];
#pragma unroll
        for (int g = 0; g < 3; ++g)
#pragma unroll
            for (int rt = 0; rt < 2; ++rt) acc[g][rt] = (f32x4){0.f, 0.f, 0.f, 0.f};
        int pw[2];
#pragma unroll
        for (int rt = 0; rt < 2; ++rt)
            pw[rt] = win_p[(half * 2 + rt) * 16 + (lane & 15)];
#pragma unroll
        for (int kt = 0; kt < 4; ++kt) {
            short8 af[2];
#pragma unroll
            for (int rt = 0; rt < 2; ++rt)
                af[rt] = *(const short8*)&h2b[pw[rt]][(lane >> 4) * 8 + kt * 32];
#pragma unroll
            for (int g = 0; g < 3; ++g) {
                short8 bf =
                    *(const short8*)(wpack + ((size_t)((g * 8 + ww) * 4 + kt) * 64 + lane) * 8);
#pragma unroll
                for (int rt = 0; rt < 2; ++rt)
                    acc[g][rt] = __builtin_amdgcn_mfma_f32_16x16x32_bf16(
                        af[rt], bf, acc[g][rt], 0, 0, 0);
            }
        }
#pragma unroll
        for (int rt = 0; rt < 2; ++rt)
#pragma unroll
            for (int reg = 0; reg < 4; ++reg) {
                int jj = (half * 2 + rt) * 16 + (lane >> 4) * 4 + reg;
                int rel = win_rel[jj];
                float rr = sig_(G[(size_t)rel * THREE_E + e] + acc[0][rt][reg] + b_r);
                float zz = sig_(G[(size_t)rel * THREE_E + E + e] + acc[1][rt][reg] + b_z);
                float nn = tanh_(G[(size_t)rel * THREE_E + 2 * E + e] +
                                 rr * (acc[2][rt][reg] + b_n));
                int p = win_p[jj];
                float h = __bfloat162float(__builtin_bit_cast(__hip_bfloat16, h2b[p][e]));
                o_emb[((size_t)(b * 3 + 2) * 64 + jj) * E + e] = (1.0f - zz) * nn + zz * h;
            }
    }
}

extern "C" void kernel_launch(void* const* d_in, const int* in_sizes, int n_in,
                              void* d_out, int out_size, void* d_ws, size_t ws_size,
                              hipStream_t stream) {
    const int* query = (const int*)d_in[0];
    const int* support = (const int*)d_in[1];
    const float* cosr = (const float*)d_in[2];
    const int2* edge = (const int2*)d_in[3];
    const float* rel_w = (const float*)d_in[4];
    const float* wih = (const float*)d_in[5];
    const float* whh = (const float*)d_in[6];
    const float* bih = (const float*)d_in[7];
    const float* bhh = (const float*)d_in[8];
    int B = in_sizes[0];      // 512
    int S = in_sizes[1];      // 16
    int R = in_sizes[4] / E;  // 200

    float* out = (float*)d_out;
    size_t o_tree = 0;
    size_t o_emb = (size_t)B * 3 * 64;
    size_t o_pidx = o_emb + (size_t)B * 3 * 64 * E;
    size_t o_pnode = o_pidx + (size_t)B * 3 * 64;
    size_t o_rel = o_pnode + (size_t)B * 3 * 64;

    char* ws = (char*)d_ws;
    int* rank = (int*)ws;      ws += 256 * 4;
    float* G = (float*)ws;     ws += (size_t)R * THREE_E * 4;
    float* emb1 = (float*)ws;  ws += (size_t)R * E * 4;
    float* GH1 = (float*)ws;   ws += (size_t)R * THREE_E * 4;
    short* wpack = (short*)ws; ws += (size_t)24 * 4 * 64 * 8 * 2;

    kAB<<<R + 96 + 1, 512, 0, stream>>>(support, cosr, rank, S, R, rel_w, wih, bih,
                                        G, whh, bhh, emb1, GH1, wpack);
    k_main<<<B, 1024, 0, stream>>>(query, edge, rank, G, GH1, emb1, wpack, bhh,
                                   out + o_tree, out + o_emb, out + o_pidx,
                                   out + o_pnode, out + o_rel);
}